// Round 9
// baseline (27.834 us; speedup 1.0000x reference)
//
#include <hip/hip_runtime.h>
#include <math.h>

#define LMAX   6
#define NRAD   20
#define NELEM  4
#define NBATCH 2000
#define NPTS   100000
#define NLMTOT 49
#define OUTROW 3920
#define PROW   76            // LDS words/pt: [0:49 Y][49:52 pad][52+6g+j: rad n=5g+j, j<5]
#define PI_F   3.14159265358979323846f
#define RADK   0.44721359549995793f   // sqrt(2/RC), RC=10
#define INV_RC 0.1f

// --- fused: one block per 2 batches (write-tail pipelining); wave w = elem w ---
__global__ __launch_bounds__(256) void sfe_kernel(
    const float* __restrict__ coords,
    const int*   __restrict__ elem_ids,
    const int*   __restrict__ batch_ids,
    float*       __restrict__ out)
{
  const int b0   = blockIdx.x * 2;
  const int t    = threadIdx.x;
  const int w    = t >> 6;       // wave = elem
  const int lane = t & 63;
  const int tl   = lane & 15;    // lm tile: {4tl..4tl+3}
  const int tn   = lane >> 4;    // n  tile: {5tn..5tn+4}

  __shared__ __align__(16) float sMem[64 * PROW];  // 19.5 KB; reused as sOut[4][980]
  __shared__ float sC[NLMTOT];
  __shared__ int   sRange[3];

  // --- wave 0: 3-target 21-ary parallel lower_bound (b0, b0+1, b0+2) ---
  if (t < 63) {
    const int g = t / 21, j = t - 21 * g;       // group g -> target b0+g
    const int tgt = b0 + g;
    const unsigned long long hm = 0x1FFFFFULL << (21 * g);
    int base = 0;
    int S = 9261;                                // 21^3; levels 9261/441/21/1
#pragma unroll
    for (int lev = 0; lev < 4; ++lev) {
      int pos = base + j * S;
      int val = (pos < NPTS) ? batch_ids[pos] : 0x7FFFFFFF;
      unsigned long long mb = __ballot(val < tgt) & hm;
      int cnt = __popcll(mb);
      if (S == 1)       base += cnt;
      else if (cnt > 0) base += (cnt - 1) * S + 1;
      S = (lev == 0) ? 441 : (lev == 1) ? 21 : 1;
    }
    if (j == 0) sRange[g] = base;
  }
  // --- wave 1: normalization constants ---
  if (t >= 64 && t < 64 + NLMTOT) {
    int lm = t - 64, l = 0;
#pragma unroll
    for (int ll = 1; ll <= LMAX; ++ll) if (lm >= ll * ll) l = ll;
    int m  = lm - l * l - l;
    int am = m < 0 ? -m : m;
    float denom = 1.f;
    for (int k = l - am + 1; k <= l + am; ++k) denom *= (float)k;
    float nlm = sqrtf((float)(2 * l + 1) / denom);
    sC[lm] = (m == 0) ? nlm : 1.4142135623730951f * nlm;
  }
  __syncthreads();

  for (int sub = 0; sub < 2; ++sub) {
    const int b     = b0 + sub;
    const int start = sRange[sub], end = sRange[sub + 1];

    float acc[4][5];
#pragma unroll
    for (int i = 0; i < 4; ++i)
#pragma unroll
      for (int j = 0; j < 5; ++j) acc[i][j] = 0.f;

    for (int c = start; c < end; c += 64) {
      int cnt = end - c; if (cnt > 64) cnt = 64;

      // --- stage SH+rad: wave 0, all 64 lanes, one point per lane ---
      if (t < 64 && lane < cnt) {
        int p = c + lane;
        float x = coords[3 * p + 0], y = coords[3 * p + 1], z = coords[3 * p + 2];
        float r    = sqrtf(x * x + y * y + z * z);
        float invr = 1.f / r;
        x *= invr; y *= invr; z *= invr;

        float cs[LMAX + 1], sn[LMAX + 1];
        cs[0] = 1.f; sn[0] = 0.f;
#pragma unroll
        for (int m = 1; m <= LMAX; ++m) {
          cs[m] = cs[m - 1] * x - sn[m - 1] * y;
          sn[m] = sn[m - 1] * x + cs[m - 1] * y;
        }
        float Q[LMAX + 1][LMAX + 1];
        Q[0][0] = 1.f;
#pragma unroll
        for (int m = 1; m <= LMAX; ++m) Q[m][m] = -(float)(2 * m - 1) * Q[m - 1][m - 1];
#pragma unroll
        for (int m = 0; m < LMAX; ++m) Q[m + 1][m] = (float)(2 * m + 1) * z * Q[m][m];
#pragma unroll
        for (int m = 0; m <= LMAX; ++m) {
#pragma unroll
          for (int ll = m + 2; ll <= LMAX; ++ll) {
            Q[ll][m] = ((float)(2 * ll - 1) * z * Q[ll - 1][m]
                      - (float)(ll + m - 1) * Q[ll - 2][m]) / (float)(ll - m);
          }
        }
        float* row = sMem + lane * PROW;
#pragma unroll
        for (int ll = 0; ll <= LMAX; ++ll) {
#pragma unroll
          for (int m = -ll; m <= ll; ++m) {
            int am = m < 0 ? -m : m;
            float v = Q[ll][am] * sC[ll * ll + ll + m];
            if (m < 0)      v *= sn[am];
            else if (m > 0) v *= cs[am];
            row[ll * ll + ll + m] = v;
          }
        }
        float a = PI_F * r * INV_RC;
        float s1, c1;
        __sincosf(a, &s1, &c1);
        float twoc = 2.f * c1, sprev = 0.f, scur = s1, scale = RADK * invr;
#pragma unroll
        for (int n = 0; n < NRAD; ++n) {
          row[52 + 6 * (n / 5) + (n % 5)] = scale * scur;
          float sx = twoc * scur - sprev; sprev = scur; scur = sx;
        }
      }

      // --- per-wave ballot of this wave's elem ---
      bool match = (lane < cnt) && (elem_ids[c + lane] == w);
      unsigned long long mask = __ballot(match);
      __syncthreads();

      // --- accumulate: walk mask bits; b128 (Y) + 2x b64 + b32 (rad), 20 FMAs/pt ---
      for (unsigned long long mm = mask; mm; mm &= mm - 1) {
        int p = (int)__ffsll(mm) - 1;
        const float* row = sMem + p * PROW;
        float4 yv = *(const float4*)(row + 4 * tl);
        float2 ra = *(const float2*)(row + 52 + 6 * tn);
        float2 rb = *(const float2*)(row + 52 + 6 * tn + 2);
        float  r4 = row[52 + 6 * tn + 4];
        float yy[4] = {yv.x, yv.y, yv.z, yv.w};
        float rr[5] = {ra.x, ra.y, rb.x, rb.y, r4};
#pragma unroll
        for (int i = 0; i < 4; ++i)
#pragma unroll
          for (int j = 0; j < 5; ++j)
            acc[i][j] += yy[i] * rr[j];
      }
      __syncthreads();
    }

    // --- epilogue: acc -> sOut[w][980], then coalesced float4 stores (async drain) ---
    float* sOut = sMem + w * 980;
#pragma unroll
    for (int i = 0; i < 4; ++i) {
      int lm = 4 * tl + i;
      if (lm < NLMTOT) {
        int l = 0;
#pragma unroll
        for (int ll = 1; ll <= LMAX; ++ll) if (lm >= ll * ll) l = ll;
        int fb = 20 * l * l, mi = lm - l * l, nm = 2 * l + 1;
#pragma unroll
        for (int j = 0; j < 5; ++j)
          sOut[fb + (5 * tn + j) * nm + mi] = acc[i][j];
      }
    }
    for (int idx = lane; idx < 245; idx += 64) {
      int f0 = 4 * idx, lw = 0;
#pragma unroll
      for (int ll = 1; ll <= LMAX; ++ll) if (f0 >= 20 * ll * ll) lw = ll;
      long long g = (long long)b * OUTROW + 80 * lw * lw
                  + (long long)w * 20 * (2 * lw + 1) + (f0 - 20 * lw * lw);
      *(float4*)(out + g) = *(const float4*)(sOut + f0);
    }
    __syncthreads();   // sMem reuse by next batch's staging (stores keep draining)
  }
}

extern "C" void kernel_launch(void* const* d_in, const int* in_sizes, int n_in,
                              void* d_out, int out_size, void* d_ws, size_t ws_size,
                              hipStream_t stream) {
  const float* coords    = (const float*)d_in[0];
  const int*   elem_ids  = (const int*)d_in[1];
  const int*   batch_ids = (const int*)d_in[2];
  float*       out       = (float*)d_out;
  sfe_kernel<<<NBATCH / 2, 256, 0, stream>>>(coords, elem_ids, batch_ids, out);
}

// Round 11
// 22.203 us; speedup vs baseline: 1.2536x; 1.2536x over previous
//
#include <hip/hip_runtime.h>
#include <math.h>

#define LMAX   6
#define NRAD   20
#define NELEM  4
#define NBATCH 2000
#define NPTS   100000
#define NLMTOT 49
#define OUTROW 3920
#define PROW   76            // LDS words/pt: [0:49 Y][49:52 pad][52+6g+j: rad n=5g+j, j<5]
#define PI_F   3.14159265358979323846f
#define RADK   0.44721359549995793f   // sqrt(2/RC), RC=10
#define INV_RC 0.1f

typedef float f32x4 __attribute__((ext_vector_type(4)));   // clang vector: nt-store OK

// --- single fused kernel: one block per batch; wave w accumulates elem w ---
// grid = 2000 (≈8 blocks/CU): cross-block overlap IS the pipeline (R9 lesson:
// halving the grid for intra-block write pipelining regressed 24.7 -> 27.8).
__global__ __launch_bounds__(256) void sfe_kernel(
    const float* __restrict__ coords,
    const int*   __restrict__ elem_ids,
    const int*   __restrict__ batch_ids,
    float*       __restrict__ out)
{
  const int b    = blockIdx.x;
  const int t    = threadIdx.x;
  const int w    = t >> 6;       // wave = elem
  const int lane = t & 63;
  const int tl   = lane & 15;    // lm tile: {4tl..4tl+3}
  const int tn   = lane >> 4;    // n  tile: {5tn..5tn+4}

  __shared__ __align__(16) float sMem[64 * PROW];  // 19.5 KB; reused as sOut[4][980]
  __shared__ float sC[NLMTOT];
  __shared__ int   sRange[2];

  // --- wave 0: 4-level 32-ary parallel lower_bound for b (lanes 0-31) and b+1 (32-63) ---
  if (t < 64) {
    const int half = t >> 5, j = t & 31;
    const int tgt  = b + half;
    const unsigned long long hm = half ? 0xFFFFFFFF00000000ULL : 0x00000000FFFFFFFFULL;
    int base = 0;
    int S = 3125;
#pragma unroll
    for (int lev = 0; lev < 4; ++lev) {
      int pos = base + j * S;
      int val = (pos < NPTS) ? batch_ids[pos] : 0x7FFFFFFF;
      unsigned long long mb = __ballot(val < tgt) & hm;
      int cnt = __popcll(mb);
      if (S == 1)       base += cnt;                 // final: exact
      else if (cnt > 0) base += (cnt - 1) * S + 1;   // range shrinks to S
      S = (lev == 0) ? 98 : (lev == 1) ? 4 : 1;
    }
    if (j == 0) sRange[half] = base;
  }
  // --- wave 1: normalization constants ---
  if (t >= 64 && t < 64 + NLMTOT) {
    int lm = t - 64, l = 0;
#pragma unroll
    for (int ll = 1; ll <= LMAX; ++ll) if (lm >= ll * ll) l = ll;
    int m  = lm - l * l - l;
    int am = m < 0 ? -m : m;
    float denom = 1.f;
    for (int k = l - am + 1; k <= l + am; ++k) denom *= (float)k;
    float nlm = sqrtf((float)(2 * l + 1) / denom);
    sC[lm] = (m == 0) ? nlm : 1.4142135623730951f * nlm;
  }
  __syncthreads();

  const int start = sRange[0], end = sRange[1];

  float acc[4][5];
#pragma unroll
  for (int i = 0; i < 4; ++i)
#pragma unroll
    for (int j = 0; j < 5; ++j) acc[i][j] = 0.f;

  for (int c = start; c < end; c += 64) {
    int cnt = end - c; if (cnt > 64) cnt = 64;

    // --- stage SH+rad: wave 0 only, ALL 64 lanes, one point per lane ---
    if (t < 64 && lane < cnt) {
      int p = c + lane;
      float x = coords[3 * p + 0], y = coords[3 * p + 1], z = coords[3 * p + 2];
      float r    = sqrtf(x * x + y * y + z * z);
      float invr = 1.f / r;
      x *= invr; y *= invr; z *= invr;

      float cs[LMAX + 1], sn[LMAX + 1];
      cs[0] = 1.f; sn[0] = 0.f;
#pragma unroll
      for (int m = 1; m <= LMAX; ++m) {
        cs[m] = cs[m - 1] * x - sn[m - 1] * y;
        sn[m] = sn[m - 1] * x + cs[m - 1] * y;
      }
      float Q[LMAX + 1][LMAX + 1];
      Q[0][0] = 1.f;
#pragma unroll
      for (int m = 1; m <= LMAX; ++m) Q[m][m] = -(float)(2 * m - 1) * Q[m - 1][m - 1];
#pragma unroll
      for (int m = 0; m < LMAX; ++m) Q[m + 1][m] = (float)(2 * m + 1) * z * Q[m][m];
#pragma unroll
      for (int m = 0; m <= LMAX; ++m) {
#pragma unroll
        for (int ll = m + 2; ll <= LMAX; ++ll) {
          Q[ll][m] = ((float)(2 * ll - 1) * z * Q[ll - 1][m]
                    - (float)(ll + m - 1) * Q[ll - 2][m]) / (float)(ll - m);
        }
      }
      float* row = sMem + lane * PROW;
#pragma unroll
      for (int ll = 0; ll <= LMAX; ++ll) {
#pragma unroll
        for (int m = -ll; m <= ll; ++m) {
          int am = m < 0 ? -m : m;
          float v = Q[ll][am] * sC[ll * ll + ll + m];
          if (m < 0)      v *= sn[am];
          else if (m > 0) v *= cs[am];
          row[ll * ll + ll + m] = v;
        }
      }
      // rad: sin(n*a) Chebyshev; tile of 6: word 52+6g+j holds n=5g+j (j<5)
      float a = PI_F * r * INV_RC;
      float s1, c1;
      __sincosf(a, &s1, &c1);
      float twoc = 2.f * c1, sprev = 0.f, scur = s1, scale = RADK * invr;
#pragma unroll
      for (int n = 0; n < NRAD; ++n) {
        row[52 + 6 * (n / 5) + (n % 5)] = scale * scur;
        float sx = twoc * scur - sprev; sprev = scur; scur = sx;
      }
    }

    // --- per-wave ballot of this wave's elem (no LDS index list) ---
    bool match = (lane < cnt) && (elem_ids[c + lane] == w);
    unsigned long long mask = __ballot(match);
    __syncthreads();

    // --- accumulate: walk mask bits; b128 (Y) + 2x b64 + b32 (rad), 20 FMAs/pt ---
    for (unsigned long long mm = mask; mm; mm &= mm - 1) {
      int p = (int)__ffsll(mm) - 1;
      const float* row = sMem + p * PROW;
      float4 yv = *(const float4*)(row + 4 * tl);
      float2 ra = *(const float2*)(row + 52 + 6 * tn);
      float2 rb = *(const float2*)(row + 52 + 6 * tn + 2);
      float  r4 = row[52 + 6 * tn + 4];
      float yy[4] = {yv.x, yv.y, yv.z, yv.w};
      float rr[5] = {ra.x, ra.y, rb.x, rb.y, r4};
#pragma unroll
      for (int i = 0; i < 4; ++i)
#pragma unroll
        for (int j = 0; j < 5; ++j)
          acc[i][j] += yy[i] * rr[j];
    }
    __syncthreads();
  }

  // --- epilogue (wave-local): acc -> sOut[w][980], then coalesced nt float4 runs ---
  float* sOut = sMem + w * 980;
#pragma unroll
  for (int i = 0; i < 4; ++i) {
    int lm = 4 * tl + i;
    if (lm < NLMTOT) {
      int l = 0;
#pragma unroll
      for (int ll = 1; ll <= LMAX; ++ll) if (lm >= ll * ll) l = ll;
      int fb = 20 * l * l, mi = lm - l * l, nm = 2 * l + 1;
#pragma unroll
      for (int j = 0; j < 5; ++j)
        sOut[fb + (5 * tn + j) * nm + mi] = acc[i][j];
    }
  }
  for (int idx = lane; idx < 245; idx += 64) {
    int f0 = 4 * idx, lw = 0;
#pragma unroll
    for (int ll = 1; ll <= LMAX; ++ll) if (f0 >= 20 * ll * ll) lw = ll;
    long long g = (long long)b * OUTROW + 80 * lw * lw
                + (long long)w * 20 * (2 * lw + 1) + (f0 - 20 * lw * lw);
    // output is write-once, never re-read: nt store skips L2 allocation
    __builtin_nontemporal_store(*(const f32x4*)(sOut + f0), (f32x4*)(out + g));
  }
}

extern "C" void kernel_launch(void* const* d_in, const int* in_sizes, int n_in,
                              void* d_out, int out_size, void* d_ws, size_t ws_size,
                              hipStream_t stream) {
  const float* coords    = (const float*)d_in[0];
  const int*   elem_ids  = (const int*)d_in[1];
  const int*   batch_ids = (const int*)d_in[2];
  float*       out       = (float*)d_out;
  sfe_kernel<<<NBATCH, 256, 0, stream>>>(coords, elem_ids, batch_ids, out);
}